// Round 11
// baseline (218.856 us; speedup 1.0000x reference)
//
#include <hip/hip_runtime.h>

#define EDIM 1024
#define NHEADS 16
#define HDIM 64
#define SEQ 2048
#define BATCH 4
#define MROWS (BATCH * SEQ)   // 8192
#define NQKV (3 * EDIM)       // 3072
#define QKB 2048              // QK buffer row stride (Q cols 0..1023, K 1024..2047)

typedef __attribute__((ext_vector_type(4))) float f32x4;
typedef __attribute__((ext_vector_type(8))) short s16x8;
typedef __attribute__((ext_vector_type(4))) short s16x4;
typedef __attribute__((ext_vector_type(4))) unsigned int u32x4;

#define AS1 __attribute__((address_space(1)))
#define AS3 __attribute__((address_space(3)))
#define GLOAD_LDS16(g, l) __builtin_amdgcn_global_load_lds( \
    (AS1 void*)(void*)(g), (AS3 void*)(void*)(l), 16, 0, 0)

static __device__ __forceinline__ unsigned short f2bf(float f) {
  unsigned int u = __builtin_bit_cast(unsigned int, f);
  u += 0x7fffu + ((u >> 16) & 1u);   // RNE
  return (unsigned short)(u >> 16);
}

static __device__ __forceinline__ float fexp2(float x) {
  float r;
  asm("v_exp_f32 %0, %1" : "=v"(r) : "v"(x));
  return r;
}

static __device__ __forceinline__ unsigned int cvtpk(float a, float b) {
  unsigned int r;
  asm("v_cvt_pk_bf16_f32 %0, %1, %2" : "=v"(r) : "v"(a), "v"(b));
  return r;
}

static __device__ __forceinline__ f32x4 mfma_bf16(s16x8 a, s16x8 b, f32x4 c) {
  return __builtin_amdgcn_mfma_f32_16x16x32_bf16(a, b, c, 0, 0, 0);
}

// counted waitcnt with compile-time literal
template <int N>
static __device__ __forceinline__ void wait_vm() {
  if constexpr (N >= 8)      asm volatile("s_waitcnt lgkmcnt(0) vmcnt(8)" ::: "memory");
  else if constexpr (N == 6) asm volatile("s_waitcnt lgkmcnt(0) vmcnt(6)" ::: "memory");
  else if constexpr (N == 4) asm volatile("s_waitcnt lgkmcnt(0) vmcnt(4)" ::: "memory");
  else if constexpr (N == 3) asm volatile("s_waitcnt lgkmcnt(0) vmcnt(3)" ::: "memory");
  else if constexpr (N == 2) asm volatile("s_waitcnt lgkmcnt(0) vmcnt(2)" ::: "memory");
  else if constexpr (N == 1) asm volatile("s_waitcnt lgkmcnt(0) vmcnt(1)" ::: "memory");
  else                       asm volatile("s_waitcnt lgkmcnt(0) vmcnt(0)" ::: "memory");
}

// one kernel converts x, w_qkv, w_proj (outputs contiguous in workspace)
__global__ void __launch_bounds__(256) cvt_all(const float* __restrict__ x,
                                               const float* __restrict__ wq,
                                               const float* __restrict__ wp,
                                               unsigned short* __restrict__ out) {
  const int i = blockIdx.x * 256 + threadIdx.x;   // float4 index
  const float* src;
  int j;
  if (i < 2097152) { src = x;  j = i; }
  else if (i < 2883584) { src = wq; j = i - 2097152; }
  else { src = wp; j = i - 2883584; }
  const float4 v = ((const float4*)src)[j];
  ushort4 o;
  o.x = f2bf(v.x); o.y = f2bf(v.y); o.z = f2bf(v.z); o.w = f2bf(v.w);
  ((ushort4*)out)[i] = o;
}

// ---------------------------------------------------------------------------
// Deep-pipelined GEMM (unchanged from round 9, verified).
// ---------------------------------------------------------------------------
template <int MODE, int BMP, int BNP>
__global__ void __launch_bounds__(512, 2) gemm256(const unsigned short* __restrict__ Ap,
                                                  const unsigned short* __restrict__ Bp,
                                                  const float* __restrict__ bias,
                                                  void* __restrict__ Cout,
                                                  int M, int N, int K) {
  extern __shared__ unsigned short lds[];   // A: [4][ASLOT] then B: [4][BSLOT]
  constexpr int ASLOT = BMP * 4096;         // ushorts per A slot (BMP*128 x 32)
  constexpr int BSLOT = BNP * 4096;
  constexpr int BBASE = 4 * ASLOT;
  constexpr int L = BMP + BNP;              // loads per thread per STAGE

  const int tid = threadIdx.x;
  const int lane = tid & 63;
  const int wave = tid >> 6;        // 0..7
  const int wr = wave >> 2;         // 0..1  (M half)
  const int wc = wave & 3;          // 0..3  (N quarter)
  const int lr = lane & 15, kg = lane >> 4;

  const int nwg = gridDim.x;        // divisible by 8
  const int q8 = nwg >> 3;
  const int wgid = (blockIdx.x & 7) * q8 + (blockIdx.x >> 3);  // XCD-bijective
  const int NBM = M >> (BMP == 2 ? 8 : 7);
  const long m0 = (long)(wgid % NBM) * (BMP * 128);
  const long n0 = (long)(wgid / NBM) * (BNP * 128);

#define STAGE(slot, kt) do {                                                   \
    _Pragma("unroll")                                                          \
    for (int i_ = 0; i_ < BMP; ++i_) {                                         \
      const int c_ = wave * BMP + i_;               /* chunk (1KB, 16 rows) */ \
      const int r_ = c_ * 16 + (lane >> 2);                                    \
      const int sc_ = ((lane & 3) ^ ((r_ >> 1) & 3)) * 8;                      \
      GLOAD_LDS16(Ap + (m0 + r_) * K + (kt) * 32 + sc_,                        \
                  &lds[(slot) * ASLOT + c_ * 512]);                            \
    }                                                                          \
    _Pragma("unroll")                                                          \
    for (int i_ = 0; i_ < BNP; ++i_) {                                         \
      const int c_ = wave * BNP + i_;                                          \
      const int r_ = c_ * 16 + (lane >> 2);                                    \
      const int sc_ = ((lane & 3) ^ ((r_ >> 1) & 3)) * 8;                      \
      GLOAD_LDS16(Bp + (n0 + r_) * K + (kt) * 32 + sc_,                        \
                  &lds[BBASE + (slot) * BSLOT + c_ * 512]);                    \
    }                                                                          \
  } while (0)

  f32x4 acc[BMP * 4][BNP * 2] = {};
  const int nk = K >> 5;            // K-tiles of 32

  STAGE(0, 0); STAGE(1, 1); STAGE(2, 2);   // 3L loads in flight
  wait_vm<2 * L>();                        // tile 0 landed
  __builtin_amdgcn_s_barrier();
  __builtin_amdgcn_sched_barrier(0);

  for (int t = 0; t < nk; ++t) {
    if (t + 3 < nk) STAGE((t + 3) & 3, t + 3);        // deep prefetch

    const unsigned short* Asl = &lds[(t & 3) * ASLOT];
    const unsigned short* Bsl = &lds[BBASE + (t & 3) * BSLOT];
    s16x8 af[BMP * 4], bf[BNP * 2];
#pragma unroll
    for (int mt = 0; mt < BMP * 4; ++mt) {
      const int r = wr * (BMP * 64) + mt * 16 + lr;
      af[mt] = *(const s16x8*)&Asl[r * 32 + ((kg * 8) ^ (((r >> 1) & 3) << 3))];
    }
#pragma unroll
    for (int nt = 0; nt < BNP * 2; ++nt) {
      const int r = wc * (BNP * 32) + nt * 16 + lr;
      bf[nt] = *(const s16x8*)&Bsl[r * 32 + ((kg * 8) ^ (((r >> 1) & 3) << 3))];
    }
    __builtin_amdgcn_s_setprio(1);
#pragma unroll
    for (int mt = 0; mt < BMP * 4; ++mt)
#pragma unroll
      for (int nt = 0; nt < BNP * 2; ++nt)
        acc[mt][nt] = mfma_bf16(af[mt], bf[nt], acc[mt][nt]);
    __builtin_amdgcn_s_setprio(0);

    if (t + 1 < nk) {
      if (t + 3 < nk)      wait_vm<2 * L>();
      else if (t + 2 < nk) wait_vm<L>();
      else                 wait_vm<0>();
      __builtin_amdgcn_s_barrier();
      __builtin_amdgcn_sched_barrier(0);
    }
  }

#pragma unroll
  for (int nt = 0; nt < BNP * 2; ++nt) {
    const long col = n0 + wc * (BNP * 32) + nt * 16 + lr;
    const float bv = (MODE == 2) ? 0.f : bias[col];
#pragma unroll
    for (int mt = 0; mt < BMP * 4; ++mt) {
#pragma unroll
      for (int r = 0; r < 4; ++r) {
        const long row = m0 + wr * (BMP * 64) + mt * 16 + kg * 4 + r;
        if (MODE == 0) {
          float v = acc[mt][nt][r] + bv;
          if (col < EDIM) v *= 0.18033688011112042f;  // 0.125 * log2(e)
          ((unsigned short*)Cout)[row * QKB + col] = f2bf(v);
        } else if (MODE == 1) {
          ((float*)Cout)[row * N + col] = acc[mt][nt][r] + bv;
        } else {
          const float v = acc[mt][nt][r] + bias[row];
          ((unsigned short*)Cout)[((col >> 11) * 1024 + row) * (long)2048 +
                                  (col & 2047)] = f2bf(v);
        }
      }
    }
  }
#undef STAGE
}

// ---------------------------------------------------------------------------
// Flash attention, KVBLK=32, 16 q-rows/wave, 4-slot counted-vmcnt pipeline.
// 512 threads / 8 waves; waves 0-3 stage K, 4-7 stage V (1 load/thread/tile).
// LDS 32 KB -> 4 blocks/CU = 32 waves/CU. grid 1024.
// K slot: [32 k][64 d] swizzled (block ^= row&7).
// V slot: [64 d][32 kv] swizzled (block ^= (d>>1)&3).
// ---------------------------------------------------------------------------
__global__ void __launch_bounds__(512, 8) attn_fwd(const unsigned short* __restrict__ qk,
                                                   const unsigned short* __restrict__ vT,
                                                   unsigned short* __restrict__ attout) {
  const int L = blockIdx.x;
  const int bh = (L & 7) * 8 + (L >> 7);   // 8 bh per XCD (4MB K/V = L2-resident)
  const int qt = (L >> 3) & 15;
  const int b = bh >> 4, h = bh & 15;
  const int q0 = qt * 128;
  const int tid = threadIdx.x, lane = tid & 63, wave = tid >> 6;  // 0..7
  const int lr = lane & 15, kg = lane >> 4;

  __shared__ unsigned short Ks[4][2048];   // [slot][k 32][d 64]  4KB each
  __shared__ unsigned short Vs[4][2048];   // [slot][d 64][kv 32] 4KB each

  const long rowbase = (long)b * SEQ;

  // waves 0-3: K rows (wave&3)*8 + lane>>3, block (lane&7)^(row&7)
  // waves 4-7: V rows (wave&3)*16 + lane>>2, block (lane&3)^((row>>1)&3)
#define ASTAGE(slot, kv0) do {                                                  \
    if (wave < 4) {                                                             \
      const int row_ = (wave & 3) * 8 + (lane >> 3);                            \
      const int col_ = ((lane & 7) ^ (lane >> 3)) << 3;                         \
      GLOAD_LDS16(qk + (rowbase + (kv0) + row_) * QKB + EDIM + h * HDIM + col_, \
                  &Ks[slot][(wave & 3) * 512]);                                 \
    } else {                                                                    \
      const int row_ = (wave & 3) * 16 + (lane >> 2);                           \
      const int col_ = ((lane & 3) ^ ((row_ >> 1) & 3)) << 3;                   \
      GLOAD_LDS16(vT + ((long)bh * HDIM + row_) * SEQ + (kv0) + col_,           \
                  &Vs[slot][(wave & 3) * 512]);                                 \
    }                                                                           \
  } while (0)

  // Q B-frags (Q pre-scaled by 0.125*log2e in the QK GEMM epilogue)
  s16x8 qf[2];
  {
    const unsigned short* qp =
        qk + (rowbase + q0 + wave * 16 + lr) * QKB + h * HDIM + kg * 8;
    qf[0] = *(const s16x8*)qp;
    qf[1] = *(const s16x8*)(qp + 32);
  }

  f32x4 l_part = {0.f, 0.f, 0.f, 0.f};
  f32x4 o_acc[4] = {};

  ASTAGE(0, 0); ASTAGE(1, 32); ASTAGE(2, 64);   // 3 loads in flight per wave
  wait_vm<2>();                                 // tile 0 landed
  __builtin_amdgcn_s_barrier();
  __builtin_amdgcn_sched_barrier(0);

  for (int t = 0; t < 64; ++t) {
    if (t + 3 < 64) ASTAGE((t + 3) & 3, (t + 3) * 32);   // deep prefetch

    const unsigned short* Kb = Ks[t & 3];
    const unsigned short* Vb = Vs[t & 3];

    // ---- QK^T (log2 domain): lane holds S[k = ct*16 + kg*4 + r][q = lr]
    f32x4 st[2];
    __builtin_amdgcn_s_setprio(1);
#pragma unroll
    for (int ct = 0; ct < 2; ++ct) {
      const int rb = (ct * 16 + lr) * 128;
      const int sw = (lr & 7) << 4;
      const s16x8 k0 = *(const s16x8*)&Kb[(rb + ((kg * 16) ^ sw)) >> 1];
      const s16x8 k1 = *(const s16x8*)&Kb[(rb + ((64 + kg * 16) ^ sw)) >> 1];
      f32x4 a = {};
      a = mfma_bf16(k0, qf[0], a);
      a = mfma_bf16(k1, qf[1], a);
      st[ct] = a;
    }
    __builtin_amdgcn_s_setprio(0);

    // ---- p = 2^s, lane-local rowsum, pack to bf16
    unsigned int pk[2][2];
    {
      f32x4 rv = {0.f, 0.f, 0.f, 0.f};
#pragma unroll
      for (int ct = 0; ct < 2; ++ct) {
        f32x4 p;
#pragma unroll
        for (int r = 0; r < 4; ++r) p[r] = fexp2(st[ct][r]);
        rv += p;
        pk[ct][0] = cvtpk(p[0], p[1]);
        pk[ct][1] = cvtpk(p[2], p[3]);
      }
      l_part += rv;
    }

    // ---- PV, zero-shuffle: sigma(kg*8+j) = (j>>2)*16 + kg*4 + (j&3)
    {
      u32x4 wv = {pk[0][0], pk[0][1], pk[1][0], pk[1][1]};
      const s16x8 pa = __builtin_bit_cast(s16x8, wv);
      __builtin_amdgcn_s_setprio(1);
#pragma unroll
      for (int dt = 0; dt < 4; ++dt) {
        const int d = dt * 16 + lr;
        const int rb = d * 64;                       // 64B per V row
        const int xs = ((d >> 1) & 3) << 4;
        const int lo = (kg & 1) << 3;
        const int b0 = (((kg >> 1) << 4) ^ xs) + lo;         // kv 4kg..+3
        const int b1 = ((32 + ((kg >> 1) << 4)) ^ xs) + lo;  // kv 16+4kg..+3
        const s16x4 v0 = *(const s16x4*)&Vb[(rb + b0) >> 1];
        const s16x4 v1 = *(const s16x4*)&Vb[(rb + b1) >> 1];
        const s16x8 vf = __builtin_shufflevector(v0, v1, 0, 1, 2, 3, 4, 5, 6, 7);
        o_acc[dt] = mfma_bf16(pa, vf, o_acc[dt]);
      }
      __builtin_amdgcn_s_setprio(0);
    }

    if (t + 1 < 64) {   // tile t+1 landed chip-wide after this barrier
      if (t + 3 < 64)      wait_vm<2>();
      else if (t + 2 < 64) wait_vm<1>();
      else                 wait_vm<0>();
      __builtin_amdgcn_s_barrier();
      __builtin_amdgcn_sched_barrier(0);
    }
  }

  // epilogue: l-reduce across kg groups, write O
  {
    float rs = (l_part[0] + l_part[1]) + (l_part[2] + l_part[3]);
    rs += __shfl_xor(rs, 16, 64);
    rs += __shfl_xor(rs, 32, 64);
#pragma unroll
    for (int r = 0; r < 4; ++r) {
      const float lq = __shfl(rs, kg * 4 + r, 64);
      const float inv = 1.0f / lq;
      const long row = rowbase + q0 + wave * 16 + kg * 4 + r;
#pragma unroll
      for (int dt = 0; dt < 4; ++dt)
        attout[row * EDIM + h * HDIM + dt * 16 + lr] = f2bf(o_acc[dt][r] * inv);
    }
  }
#undef ASTAGE
}

extern "C" void kernel_launch(void* const* d_in, const int* in_sizes, int n_in,
                              void* d_out, int out_size, void* d_ws, size_t ws_size,
                              hipStream_t stream) {
  const float* x      = (const float*)d_in[0];
  const float* w_qkv  = (const float*)d_in[1];
  const float* b_qkv  = (const float*)d_in[2];
  const float* w_proj = (const float*)d_in[3];
  const float* b_proj = (const float*)d_in[4];

  unsigned short* xb   = (unsigned short*)d_ws;              // 8.39M elems
  unsigned short* wqb  = xb   + (size_t)MROWS * EDIM;        // 3.15M
  unsigned short* wpb  = wqb  + (size_t)NQKV * EDIM;         // 1.05M
  unsigned short* qkb  = wpb  + (size_t)EDIM * EDIM;         // 16.8M ([8192][2048])
  unsigned short* attb = qkb  + (size_t)MROWS * QKB;         // 8.39M
  unsigned short* vTb  = attb + (size_t)MROWS * EDIM;        // 8.39M ([1024][8192])

  const int sh22 = 131072;  // 4 slots x (16+16) KB
  const int sh12 = 98304;   // 4 slots x ( 8+16) KB
  const int sh21 = 98304;   // 4 slots x (16+ 8) KB
  hipFuncSetAttribute((const void*)gemm256<0, 2, 2>,
                      hipFuncAttributeMaxDynamicSharedMemorySize, sh22);
  hipFuncSetAttribute((const void*)gemm256<2, 1, 2>,
                      hipFuncAttributeMaxDynamicSharedMemorySize, sh12);
  hipFuncSetAttribute((const void*)gemm256<1, 2, 1>,
                      hipFuncAttributeMaxDynamicSharedMemorySize, sh21);

  cvt_all<<<12288, 256, 0, stream>>>(x, w_qkv, w_proj, xb);

  // QK projection: [8192][2048] (Q pre-scaled into log2 domain). 256 wgs.
  gemm256<0, 2, 2><<<(MROWS / 256) * (QKB / 256), 512, sh22, stream>>>(
      xb, wqb, b_qkv, qkb, MROWS, QKB, EDIM);

  // V^T directly (swapped operands -> coalesced transposed store). 128x256 tile.
  gemm256<2, 1, 2><<<(EDIM / 128) * (MROWS / 256), 512, sh12, stream>>>(
      wqb + (size_t)2048 * EDIM, xb, b_qkv + 2048, vTb, EDIM, MROWS, EDIM);

  attn_fwd<<<1024, 512, 0, stream>>>(qkb, vTb, attb);

  // proj: 256x128 tile.
  gemm256<1, 2, 1><<<(MROWS / 256) * (EDIM / 128), 512, sh21, stream>>>(
      attb, wpb, b_proj, d_out, MROWS, EDIM, EDIM);
}

// Round 12
// 190.495 us; speedup vs baseline: 1.1489x; 1.1489x over previous
//
#include <hip/hip_runtime.h>

#define EDIM 1024
#define NHEADS 16
#define HDIM 64
#define SEQ 2048
#define BATCH 4
#define MROWS (BATCH * SEQ)   // 8192
#define NQKV (3 * EDIM)       // 3072
#define QKB 2048              // QK buffer row stride (Q cols 0..1023, K 1024..2047)

typedef __attribute__((ext_vector_type(4))) float f32x4;
typedef __attribute__((ext_vector_type(8))) short s16x8;
typedef __attribute__((ext_vector_type(4))) short s16x4;
typedef __attribute__((ext_vector_type(4))) unsigned int u32x4;

#define AS1 __attribute__((address_space(1)))
#define AS3 __attribute__((address_space(3)))
#define GLOAD_LDS16(g, l) __builtin_amdgcn_global_load_lds( \
    (AS1 void*)(void*)(g), (AS3 void*)(void*)(l), 16, 0, 0)

static __device__ __forceinline__ unsigned short f2bf(float f) {
  unsigned int u = __builtin_bit_cast(unsigned int, f);
  u += 0x7fffu + ((u >> 16) & 1u);   // RNE
  return (unsigned short)(u >> 16);
}

static __device__ __forceinline__ float fexp2(float x) {
  float r;
  asm("v_exp_f32 %0, %1" : "=v"(r) : "v"(x));
  return r;
}

static __device__ __forceinline__ unsigned int cvtpk(float a, float b) {
  unsigned int r;
  asm("v_cvt_pk_bf16_f32 %0, %1, %2" : "=v"(r) : "v"(a), "v"(b));
  return r;
}

static __device__ __forceinline__ f32x4 mfma_bf16(s16x8 a, s16x8 b, f32x4 c) {
  return __builtin_amdgcn_mfma_f32_16x16x32_bf16(a, b, c, 0, 0, 0);
}

// counted waitcnt with compile-time literal
template <int N>
static __device__ __forceinline__ void wait_vm() {
  if constexpr (N >= 8)      asm volatile("s_waitcnt lgkmcnt(0) vmcnt(8)" ::: "memory");
  else if constexpr (N == 6) asm volatile("s_waitcnt lgkmcnt(0) vmcnt(6)" ::: "memory");
  else if constexpr (N == 4) asm volatile("s_waitcnt lgkmcnt(0) vmcnt(4)" ::: "memory");
  else if constexpr (N == 3) asm volatile("s_waitcnt lgkmcnt(0) vmcnt(3)" ::: "memory");
  else if constexpr (N == 2) asm volatile("s_waitcnt lgkmcnt(0) vmcnt(2)" ::: "memory");
  else                       asm volatile("s_waitcnt lgkmcnt(0) vmcnt(0)" ::: "memory");
}

// one kernel converts x, w_qkv, w_proj (outputs contiguous in workspace)
__global__ void __launch_bounds__(256) cvt_all(const float* __restrict__ x,
                                               const float* __restrict__ wq,
                                               const float* __restrict__ wp,
                                               unsigned short* __restrict__ out) {
  const int i = blockIdx.x * 256 + threadIdx.x;   // float4 index
  const float* src;
  int j;
  if (i < 2097152) { src = x;  j = i; }
  else if (i < 2883584) { src = wq; j = i - 2097152; }
  else { src = wp; j = i - 2883584; }
  const float4 v = ((const float4*)src)[j];
  ushort4 o;
  o.x = f2bf(v.x); o.y = f2bf(v.y); o.z = f2bf(v.z); o.w = f2bf(v.w);
  ((ushort4*)out)[i] = o;
}

// ---------------------------------------------------------------------------
// Deep-pipelined GEMM (round-9 structure, verified).
// ---------------------------------------------------------------------------
template <int MODE, int BMP, int BNP>
__global__ void __launch_bounds__(512, 2) gemm256(const unsigned short* __restrict__ Ap,
                                                  const unsigned short* __restrict__ Bp,
                                                  const float* __restrict__ bias,
                                                  void* __restrict__ Cout,
                                                  int M, int N, int K) {
  extern __shared__ unsigned short lds[];   // A: [4][ASLOT] then B: [4][BSLOT]
  constexpr int ASLOT = BMP * 4096;         // ushorts per A slot (BMP*128 x 32)
  constexpr int BSLOT = BNP * 4096;
  constexpr int BBASE = 4 * ASLOT;
  constexpr int L = BMP + BNP;              // loads per thread per STAGE

  const int tid = threadIdx.x;
  const int lane = tid & 63;
  const int wave = tid >> 6;        // 0..7
  const int wr = wave >> 2;         // 0..1  (M half)
  const int wc = wave & 3;          // 0..3  (N quarter)
  const int lr = lane & 15, kg = lane >> 4;

  const int nwg = gridDim.x;        // divisible by 8
  const int q8 = nwg >> 3;
  const int wgid = (blockIdx.x & 7) * q8 + (blockIdx.x >> 3);  // XCD-bijective
  const int NBM = M >> (BMP == 2 ? 8 : 7);
  const long m0 = (long)(wgid % NBM) * (BMP * 128);
  const long n0 = (long)(wgid / NBM) * (BNP * 128);

#define STAGE(slot, kt) do {                                                   \
    _Pragma("unroll")                                                          \
    for (int i_ = 0; i_ < BMP; ++i_) {                                         \
      const int c_ = wave * BMP + i_;               /* chunk (1KB, 16 rows) */ \
      const int r_ = c_ * 16 + (lane >> 2);                                    \
      const int sc_ = ((lane & 3) ^ ((r_ >> 1) & 3)) * 8;                      \
      GLOAD_LDS16(Ap + (m0 + r_) * K + (kt) * 32 + sc_,                        \
                  &lds[(slot) * ASLOT + c_ * 512]);                            \
    }                                                                          \
    _Pragma("unroll")                                                          \
    for (int i_ = 0; i_ < BNP; ++i_) {                                         \
      const int c_ = wave * BNP + i_;                                          \
      const int r_ = c_ * 16 + (lane >> 2);                                    \
      const int sc_ = ((lane & 3) ^ ((r_ >> 1) & 3)) * 8;                      \
      GLOAD_LDS16(Bp + (n0 + r_) * K + (kt) * 32 + sc_,                        \
                  &lds[BBASE + (slot) * BSLOT + c_ * 512]);                    \
    }                                                                          \
  } while (0)

  f32x4 acc[BMP * 4][BNP * 2] = {};
  const int nk = K >> 5;            // K-tiles of 32

  STAGE(0, 0); STAGE(1, 1); STAGE(2, 2);   // 3L loads in flight
  wait_vm<2 * L>();                        // tile 0 landed
  __builtin_amdgcn_s_barrier();
  __builtin_amdgcn_sched_barrier(0);

  for (int t = 0; t < nk; ++t) {
    if (t + 3 < nk) STAGE((t + 3) & 3, t + 3);        // deep prefetch

    const unsigned short* Asl = &lds[(t & 3) * ASLOT];
    const unsigned short* Bsl = &lds[BBASE + (t & 3) * BSLOT];
    s16x8 af[BMP * 4], bf[BNP * 2];
#pragma unroll
    for (int mt = 0; mt < BMP * 4; ++mt) {
      const int r = wr * (BMP * 64) + mt * 16 + lr;
      af[mt] = *(const s16x8*)&Asl[r * 32 + ((kg * 8) ^ (((r >> 1) & 3) << 3))];
    }
#pragma unroll
    for (int nt = 0; nt < BNP * 2; ++nt) {
      const int r = wc * (BNP * 32) + nt * 16 + lr;
      bf[nt] = *(const s16x8*)&Bsl[r * 32 + ((kg * 8) ^ (((r >> 1) & 3) << 3))];
    }
    __builtin_amdgcn_s_setprio(1);
#pragma unroll
    for (int mt = 0; mt < BMP * 4; ++mt)
#pragma unroll
      for (int nt = 0; nt < BNP * 2; ++nt)
        acc[mt][nt] = mfma_bf16(af[mt], bf[nt], acc[mt][nt]);
    __builtin_amdgcn_s_setprio(0);

    if (t + 1 < nk) {
      if (t + 3 < nk)      wait_vm<2 * L>();
      else if (t + 2 < nk) wait_vm<L>();
      else                 wait_vm<0>();
      __builtin_amdgcn_s_barrier();
      __builtin_amdgcn_sched_barrier(0);
    }
  }

#pragma unroll
  for (int nt = 0; nt < BNP * 2; ++nt) {
    const long col = n0 + wc * (BNP * 32) + nt * 16 + lr;
    const float bv = (MODE == 2) ? 0.f : bias[col];
#pragma unroll
    for (int mt = 0; mt < BMP * 4; ++mt) {
#pragma unroll
      for (int r = 0; r < 4; ++r) {
        const long row = m0 + wr * (BMP * 64) + mt * 16 + kg * 4 + r;
        if (MODE == 0) {
          float v = acc[mt][nt][r] + bv;
          if (col < EDIM) v *= 0.18033688011112042f;  // 0.125 * log2(e)
          ((unsigned short*)Cout)[row * QKB + col] = f2bf(v);
        } else if (MODE == 1) {
          ((float*)Cout)[row * N + col] = acc[mt][nt][r] + bv;
        } else {
          const float v = acc[mt][nt][r] + bias[row];
          ((unsigned short*)Cout)[((col >> 11) * 1024 + row) * (long)2048 +
                                  (col & 2047)] = f2bf(v);
        }
      }
    }
  }
#undef STAGE
}

// ---------------------------------------------------------------------------
// Flash attention — round-10 configuration (verified best: 89.4 µs).
// KVBLK=64, 32 q-rows/wave, 512 thr / 8 waves, 4-slot counted-vmcnt pipeline,
// 64 KB LDS -> 2 blocks/CU. grid 512: bh = (L&7)*8 + (L>>6), qt = (L>>3)&7.
// ---------------------------------------------------------------------------
__global__ void __launch_bounds__(512, 4) attn_fwd(const unsigned short* __restrict__ qk,
                                                   const unsigned short* __restrict__ vT,
                                                   unsigned short* __restrict__ attout) {
  const int L = blockIdx.x;
  const int bh = (L & 7) * 8 + (L >> 6);
  const int qt = (L >> 3) & 7;
  const int b = bh >> 4, h = bh & 15;
  const int q0 = qt * 256;
  const int tid = threadIdx.x, lane = tid & 63, wave = tid >> 6;  // wave 0..7
  const int lr = lane & 15, kg = lane >> 4;

  __shared__ unsigned short Ks[4][4096];   // [slot][k 64][d 64] swizzled
  __shared__ unsigned short Vs[4][4096];   // [slot][d 64][kv 64] swizzled

  const long rowbase = (long)b * SEQ;

  // per-thread: 1 K-load + 1 V-load per tile (L=2). 8 waves cover 64 rows.
#define ASTAGE(slot, kv0) do {                                                  \
    const int row_ = wave * 8 + (lane >> 3);                                    \
    const int col_ = ((lane & 7) ^ (lane >> 3)) << 3;                           \
    GLOAD_LDS16(qk + (rowbase + (kv0) + row_) * QKB + EDIM + h * HDIM + col_,   \
                &Ks[slot][wave * 512]);                                         \
    GLOAD_LDS16(vT + ((long)bh * HDIM + row_) * SEQ + (kv0) + col_,             \
                &Vs[slot][wave * 512]);                                         \
  } while (0)

  // Q B-frags (Q pre-scaled by 0.125*log2e in the QK GEMM epilogue)
  s16x8 qf[2][2];
#pragma unroll
  for (int qs = 0; qs < 2; ++qs) {
    const unsigned short* qp =
        qk + (rowbase + q0 + wave * 32 + qs * 16 + lr) * QKB + h * HDIM + kg * 8;
    qf[qs][0] = *(const s16x8*)qp;
    qf[qs][1] = *(const s16x8*)(qp + 32);
  }

  f32x4 l_part[2] = {{0.f, 0.f, 0.f, 0.f}, {0.f, 0.f, 0.f, 0.f}};
  f32x4 o_acc[2][4] = {};

  ASTAGE(0, 0); ASTAGE(1, 64); ASTAGE(2, 128);   // 6 loads in flight
  wait_vm<4>();                                  // tile 0 landed
  __builtin_amdgcn_s_barrier();
  __builtin_amdgcn_sched_barrier(0);

  for (int t = 0; t < 32; ++t) {
    if (t + 3 < 32) ASTAGE((t + 3) & 3, (t + 3) * 64);   // deep prefetch

    const unsigned short* Kb = Ks[t & 3];
    const unsigned short* Vb = Vs[t & 3];

    // ---- QK^T (log2 domain): lane holds S[k=ct*16+kg*4+r][q=lr] per qs
    f32x4 st[2][4];
    __builtin_amdgcn_s_setprio(1);
#pragma unroll
    for (int ct = 0; ct < 4; ++ct) {
      const int rb = (ct * 16 + lr) * 128;
      const int sw = (lr & 7) << 4;
      const s16x8 k0 = *(const s16x8*)&Kb[(rb + ((kg * 16) ^ sw)) >> 1];
      const s16x8 k1 = *(const s16x8*)&Kb[(rb + ((64 + kg * 16) ^ sw)) >> 1];
#pragma unroll
      for (int qs = 0; qs < 2; ++qs) {
        f32x4 a = {};
        a = mfma_bf16(k0, qf[qs][0], a);
        a = mfma_bf16(k1, qf[qs][1], a);
        st[qs][ct] = a;
      }
    }
    __builtin_amdgcn_s_setprio(0);

    // ---- p = 2^s, lane-local rowsum, pack to bf16
    unsigned int pk[2][4][2];
#pragma unroll
    for (int qs = 0; qs < 2; ++qs) {
      f32x4 rv = {0.f, 0.f, 0.f, 0.f};
#pragma unroll
      for (int ct = 0; ct < 4; ++ct) {
        f32x4 p;
#pragma unroll
        for (int r = 0; r < 4; ++r) p[r] = fexp2(st[qs][ct][r]);
        rv += p;
        pk[qs][ct][0] = cvtpk(p[0], p[1]);
        pk[qs][ct][1] = cvtpk(p[2], p[3]);
      }
      l_part[qs] += rv;
    }

    // ---- PV, zero-shuffle: sigma(kc,kg,j)=32kc+16(j>>2)+4kg+(j&3) on P and V
#pragma unroll
    for (int kc = 0; kc < 2; ++kc) {
      s16x8 pa[2];
#pragma unroll
      for (int qs = 0; qs < 2; ++qs) {
        u32x4 wv = {pk[qs][2 * kc][0], pk[qs][2 * kc][1],
                    pk[qs][2 * kc + 1][0], pk[qs][2 * kc + 1][1]};
        pa[qs] = __builtin_bit_cast(s16x8, wv);
      }
      __builtin_amdgcn_s_setprio(1);
#pragma unroll
      for (int dt = 0; dt < 4; ++dt) {
        const int rb = (dt * 16 + lr) * 128;
        const int c0 = (64 * kc + 8 * kg) ^ ((lr & 7) << 4);
        const s16x4 v0 = *(const s16x4*)&Vb[(rb + c0) >> 1];
        const s16x4 v1 = *(const s16x4*)&Vb[(rb + (c0 ^ 32)) >> 1];
        const s16x8 vf = __builtin_shufflevector(v0, v1, 0, 1, 2, 3, 4, 5, 6, 7);
#pragma unroll
        for (int qs = 0; qs < 2; ++qs)
          o_acc[qs][dt] = mfma_bf16(pa[qs], vf, o_acc[qs][dt]);
      }
      __builtin_amdgcn_s_setprio(0);
    }

    if (t + 1 < 32) {   // tile t+1 landed chip-wide after this barrier
      if (t + 3 < 32)      wait_vm<4>();
      else if (t + 2 < 32) wait_vm<2>();
      else                 wait_vm<0>();
      __builtin_amdgcn_s_barrier();
      __builtin_amdgcn_sched_barrier(0);
    }
  }

#pragma unroll
  for (int qs = 0; qs < 2; ++qs) {
    float rs = (l_part[qs][0] + l_part[qs][1]) + (l_part[qs][2] + l_part[qs][3]);
    rs += __shfl_xor(rs, 16, 64);
    rs += __shfl_xor(rs, 32, 64);
#pragma unroll
    for (int r = 0; r < 4; ++r) {
      const float lq = __shfl(rs, kg * 4 + r, 64);
      const float inv = 1.0f / lq;
      const long row = rowbase + q0 + wave * 32 + qs * 16 + kg * 4 + r;
#pragma unroll
      for (int dt = 0; dt < 4; ++dt)
        attout[row * EDIM + h * HDIM + dt * 16 + lr] = f2bf(o_acc[qs][dt][r] * inv);
    }
  }
#undef ASTAGE
}

extern "C" void kernel_launch(void* const* d_in, const int* in_sizes, int n_in,
                              void* d_out, int out_size, void* d_ws, size_t ws_size,
                              hipStream_t stream) {
  const float* x      = (const float*)d_in[0];
  const float* w_qkv  = (const float*)d_in[1];
  const float* b_qkv  = (const float*)d_in[2];
  const float* w_proj = (const float*)d_in[3];
  const float* b_proj = (const float*)d_in[4];

  unsigned short* xb   = (unsigned short*)d_ws;              // 8.39M elems
  unsigned short* wqb  = xb   + (size_t)MROWS * EDIM;        // 3.15M
  unsigned short* wpb  = wqb  + (size_t)NQKV * EDIM;         // 1.05M
  unsigned short* qkb  = wpb  + (size_t)EDIM * EDIM;         // 16.8M ([8192][2048])
  unsigned short* attb = qkb  + (size_t)MROWS * QKB;         // 8.39M
  unsigned short* vTb  = attb + (size_t)MROWS * EDIM;        // 8.39M ([1024][8192])

  const int sh22 = 131072;  // 4 slots x (16+16) KB
  const int sh12 = 98304;   // 4 slots x ( 8+16) KB
  const int sh21 = 98304;   // 4 slots x (16+ 8) KB
  hipFuncSetAttribute((const void*)gemm256<0, 2, 2>,
                      hipFuncAttributeMaxDynamicSharedMemorySize, sh22);
  hipFuncSetAttribute((const void*)gemm256<2, 1, 2>,
                      hipFuncAttributeMaxDynamicSharedMemorySize, sh12);
  hipFuncSetAttribute((const void*)gemm256<1, 2, 1>,
                      hipFuncAttributeMaxDynamicSharedMemorySize, sh21);

  cvt_all<<<12288, 256, 0, stream>>>(x, w_qkv, w_proj, xb);

  // QK projection: [8192][2048] (Q pre-scaled into log2 domain). 256 wgs.
  gemm256<0, 2, 2><<<(MROWS / 256) * (QKB / 256), 512, sh22, stream>>>(
      xb, wqb, b_qkv, qkb, MROWS, QKB, EDIM);

  // V^T directly (swapped operands -> coalesced transposed store). 128x256 tile.
  gemm256<2, 1, 2><<<(EDIM / 128) * (MROWS / 256), 512, sh12, stream>>>(
      wqb + (size_t)2048 * EDIM, xb, b_qkv + 2048, vTb, EDIM, MROWS, EDIM);

  attn_fwd<<<512, 512, 0, stream>>>(qkb, vTb, attb);

  // proj: 256x128 tile.
  gemm256<1, 2, 1><<<(MROWS / 256) * (EDIM / 128), 512, sh21, stream>>>(
      attb, wpb, b_proj, d_out, MROWS, EDIM, EDIM);
}

// Round 14
// 187.353 us; speedup vs baseline: 1.1681x; 1.0168x over previous
//
#include <hip/hip_runtime.h>

#define EDIM 1024
#define NHEADS 16
#define HDIM 64
#define SEQ 2048
#define BATCH 4
#define MROWS (BATCH * SEQ)   // 8192
#define NQKV (3 * EDIM)       // 3072
#define QKB 2048              // QK buffer row stride (Q cols 0..1023, K 1024..2047)

typedef __attribute__((ext_vector_type(4))) float f32x4;
typedef __attribute__((ext_vector_type(8))) short s16x8;
typedef __attribute__((ext_vector_type(4))) short s16x4;
typedef __attribute__((ext_vector_type(4))) unsigned int u32x4;

#define AS1 __attribute__((address_space(1)))
#define AS3 __attribute__((address_space(3)))
#define GLOAD_LDS16(g, l) __builtin_amdgcn_global_load_lds( \
    (AS1 void*)(void*)(g), (AS3 void*)(void*)(l), 16, 0, 0)

static __device__ __forceinline__ unsigned short f2bf(float f) {
  unsigned int u = __builtin_bit_cast(unsigned int, f);
  u += 0x7fffu + ((u >> 16) & 1u);   // RNE
  return (unsigned short)(u >> 16);
}

static __device__ __forceinline__ float fexp2(float x) {
  float r;
  asm("v_exp_f32 %0, %1" : "=v"(r) : "v"(x));
  return r;
}

static __device__ __forceinline__ unsigned int cvtpk(float a, float b) {
  unsigned int r;
  asm("v_cvt_pk_bf16_f32 %0, %1, %2" : "=v"(r) : "v"(a), "v"(b));
  return r;
}

static __device__ __forceinline__ f32x4 mfma_bf16(s16x8 a, s16x8 b, f32x4 c) {
  return __builtin_amdgcn_mfma_f32_16x16x32_bf16(a, b, c, 0, 0, 0);
}

// counted waitcnt with compile-time literal
template <int N>
static __device__ __forceinline__ void wait_vm() {
  if constexpr (N >= 8)      asm volatile("s_waitcnt lgkmcnt(0) vmcnt(8)" ::: "memory");
  else if constexpr (N == 6) asm volatile("s_waitcnt lgkmcnt(0) vmcnt(6)" ::: "memory");
  else if constexpr (N == 4) asm volatile("s_waitcnt lgkmcnt(0) vmcnt(4)" ::: "memory");
  else if constexpr (N == 3) asm volatile("s_waitcnt lgkmcnt(0) vmcnt(3)" ::: "memory");
  else if constexpr (N == 2) asm volatile("s_waitcnt lgkmcnt(0) vmcnt(2)" ::: "memory");
  else                       asm volatile("s_waitcnt lgkmcnt(0) vmcnt(0)" ::: "memory");
}

// one kernel converts x, w_qkv, w_proj (outputs contiguous in workspace)
__global__ void __launch_bounds__(256) cvt_all(const float* __restrict__ x,
                                               const float* __restrict__ wq,
                                               const float* __restrict__ wp,
                                               unsigned short* __restrict__ out) {
  const int i = blockIdx.x * 256 + threadIdx.x;   // float4 index
  const float* src;
  int j;
  if (i < 2097152) { src = x;  j = i; }
  else if (i < 2883584) { src = wq; j = i - 2097152; }
  else { src = wp; j = i - 2883584; }
  const float4 v = ((const float4*)src)[j];
  ushort4 o;
  o.x = f2bf(v.x); o.y = f2bf(v.y); o.z = f2bf(v.z); o.w = f2bf(v.w);
  ((ushort4*)out)[i] = o;
}

// ---------------------------------------------------------------------------
// 8-phase deep-pipelined GEMM (m201-class schedule), tile (BMP*128)x(BNP*128),
// BK=64. Per phase: {ds_read quadrant frags || stage one half-tile -> barrier
// -> lgkmcnt(0) -> MFMA quadrant -> barrier}; vmcnt(2*BNP) only at Ph4/Ph8.
// r13 fix: LAST iteration's Ph4 must drain vmcnt(0) — its Ph3/4 stages are
// skipped, so the steady-state count would leave A[1] (read by Ph5-8) in
// flight (counter-walk verified for all BMP/BNP shapes).
// MODE 0: QK epilogue; MODE 1: proj (f32); MODE 2: V^T scattered store.
// ---------------------------------------------------------------------------
template <int MODE, int BMP, int BNP>
__global__ void __launch_bounds__(512, 2) gemm8p(const unsigned short* __restrict__ Ap,
                                                 const unsigned short* __restrict__ Bp,
                                                 const float* __restrict__ bias,
                                                 void* __restrict__ Cout,
                                                 int M, int N, int K) {
  extern __shared__ unsigned short lds[];
  constexpr int AHALF = BMP * 4096;   // u16: (BMP*64) rows x 64 cols
  constexpr int BHALF = BNP * 4096;
  constexpr int BBASE = 4 * AHALF;    // A region = 2 buf x 2 half

  const int tid = threadIdx.x;
  const int lane = tid & 63;
  const int wave = tid >> 6;        // 0..7
  const int wr = wave >> 2;         // 0..1  (M half)
  const int wc = wave & 3;          // 0..3  (N quarter)
  const int lr = lane & 15, kg = lane >> 4;

  const int nwg = gridDim.x;        // divisible by 8
  const int q8 = nwg >> 3;
  const int wgid = (blockIdx.x & 7) * q8 + (blockIdx.x >> 3);  // XCD-bijective
  const int NBM = M >> (BMP == 2 ? 8 : 7);
  const long m0 = (long)(wgid % NBM) * (BMP * 128);
  const long n0 = (long)(wgid / NBM) * (BNP * 128);

  // stage one half-tile; LDS linear dest, inverse-swizzled global source
  // (data row r, col-block c lives at LDS block c ^ (r&7))
#define SA(buf, half, kt) do {                                                  \
    _Pragma("unroll")                                                           \
    for (int i_ = 0; i_ < BMP; ++i_) {                                          \
      const int rh_ = i_ * 64 + wave * 8 + (lane >> 3);                         \
      const int ce_ = ((lane & 7) ^ (lane >> 3)) * 8;                           \
      GLOAD_LDS16(Ap + (m0 + (half) * (BMP * 64) + rh_) * K + (kt) * 64 + ce_,  \
                  &lds[(buf) * 2 * AHALF + (half) * AHALF + i_ * 4096 + wave * 512]); \
    } } while (0)
#define SB(buf, half, kt) do {                                                  \
    _Pragma("unroll")                                                           \
    for (int i_ = 0; i_ < BNP; ++i_) {                                          \
      const int rh_ = i_ * 64 + wave * 8 + (lane >> 3);                         \
      const int ce_ = ((lane & 7) ^ (lane >> 3)) * 8;                           \
      GLOAD_LDS16(Bp + (n0 + (half) * (BNP * 64) + rh_) * K + (kt) * 64 + ce_,  \
                  &lds[BBASE + (buf) * 2 * BHALF + (half) * BHALF + i_ * 4096 + wave * 512]); \
    } } while (0)

#define PH_ENTER() do { __builtin_amdgcn_s_barrier();                           \
    asm volatile("s_waitcnt lgkmcnt(0)" ::: "memory");                          \
    __builtin_amdgcn_sched_barrier(0); } while (0)
#define PH_EXIT() __builtin_amdgcn_s_barrier()
#define PH_EXIT_VM() do { wait_vm<2 * BNP>();                                   \
    __builtin_amdgcn_sched_barrier(0);                                          \
    __builtin_amdgcn_s_barrier(); } while (0)
#define PH_EXIT_VM0() do { wait_vm<0>();                                        \
    __builtin_amdgcn_sched_barrier(0);                                          \
    __builtin_amdgcn_s_barrier(); } while (0)

  f32x4 acc[BMP * 4][BNP * 2] = {};
  s16x8 af[2 * BMP][2], bf0[BNP][2], bf1[BNP][2];

  // A frags for quadrant qm of buffer `buf` (my half = wr)
  auto LA = [&](int buf, int qm) {
#pragma unroll
    for (int m = 0; m < 2 * BMP; ++m) {
      const int rh = qm * (BMP * 32) + m * 16 + lr;
      const int ro = (buf * 2 + wr) * AHALF + rh * 64;
#pragma unroll
      for (int ks = 0; ks < 2; ++ks)
        af[m][ks] = *(const s16x8*)
            &lds[ro + (((ks * 64 + kg * 16) ^ ((rh & 7) << 4)) >> 1)];
    }
  };
  // B frags for quadrant qn into the given register set (my half = wc>>1)
  auto LB = [&](int buf, int qn, s16x8 (&bf)[BNP][2]) {
#pragma unroll
    for (int n = 0; n < BNP; ++n) {
      const int rh = (wc & 1) * (BNP * 32) + qn * (BNP * 16) + n * 16 + lr;
      const int ro = BBASE + (buf * 2 + (wc >> 1)) * BHALF + rh * 64;
#pragma unroll
      for (int ks = 0; ks < 2; ++ks)
        bf[n][ks] = *(const s16x8*)
            &lds[ro + (((ks * 64 + kg * 16) ^ ((rh & 7) << 4)) >> 1)];
    }
  };
  auto MM = [&](int qm, int qn, s16x8 (&bf)[BNP][2]) {
    __builtin_amdgcn_s_setprio(1);
#pragma unroll
    for (int m = 0; m < 2 * BMP; ++m)
#pragma unroll
      for (int n = 0; n < BNP; ++n)
#pragma unroll
        for (int ks = 0; ks < 2; ++ks)
          acc[qm * 2 * BMP + m][qn * BNP + n] =
              mfma_bf16(af[m][ks], bf[n][ks], acc[qm * 2 * BMP + m][qn * BNP + n]);
    __builtin_amdgcn_s_setprio(0);
  };

  const int nk = K >> 6;      // 64-wide K tiles (16)
  const int nit = nk >> 1;    // 8 iterations, 2 K-tiles each

  // prologue: tile0 fully + tile1's B halves
  SB(0, 0, 0); SB(0, 1, 0);
  SA(0, 0, 0); SA(0, 1, 0);
  SB(1, 0, 1); SB(1, 1, 1);
  wait_vm<2 * BNP>();                      // tile0 landed; tile1-B in flight
  __builtin_amdgcn_sched_barrier(0);
  __builtin_amdgcn_s_barrier();
  __builtin_amdgcn_sched_barrier(0);

  for (int it = 0; it < nit; ++it) {
    const int ta = 2 * it, tb = 2 * it + 1;
    // Ph1: Q(0,0) of ta; stage A[tb] h0
    LA(0, 0); LB(0, 0, bf0);
    SA(1, 0, tb);
    PH_ENTER(); MM(0, 0, bf0); PH_EXIT();
    // Ph2: Q(0,1) of ta; stage A[tb] h1
    LB(0, 1, bf1);
    SA(1, 1, tb);
    PH_ENTER(); MM(0, 1, bf1); PH_EXIT();
    // Ph3: Q(1,0) of ta; stage B[ta+2] h0   (B buf0 dead after Ph2)
    LA(0, 1);
    if (ta + 2 < nk) SB(0, 0, ta + 2);
    PH_ENTER(); MM(1, 0, bf0); PH_EXIT();
    // Ph4: Q(1,1) of ta; stage B[ta+2] h1; counted drain.
    // r13 fix: last iteration skipped Ph3/4 stages -> steady count would
    // leave A[1] (read by Ph5-8) in flight; drain fully instead.
    if (ta + 2 < nk) SB(0, 1, ta + 2);
    PH_ENTER(); MM(1, 1, bf1);
    if (it + 1 < nit) { PH_EXIT_VM(); } else { PH_EXIT_VM0(); }
    // Ph5: Q(0,0) of tb; stage A[ta+2] h0   (A buf0 dead after Ph3)
    LA(1, 0); LB(1, 0, bf0);
    if (ta + 2 < nk) SA(0, 0, ta + 2);
    PH_ENTER(); MM(0, 0, bf0); PH_EXIT();
    // Ph6: Q(0,1) of tb; stage A[ta+2] h1
    LB(1, 1, bf1);
    if (ta + 2 < nk) SA(0, 1, ta + 2);
    PH_ENTER(); MM(0, 1, bf1); PH_EXIT();
    // Ph7: Q(1,0) of tb; stage B[tb+2] h0   (B buf1 dead after Ph6)
    LA(1, 1);
    if (tb + 2 < nk) SB(1, 0, tb + 2);
    PH_ENTER(); MM(1, 0, bf0); PH_EXIT();
    // Ph8: Q(1,1) of tb; stage B[tb+2] h1; counted drain
    if (tb + 2 < nk) SB(1, 1, tb + 2);
    PH_ENTER(); MM(1, 1, bf1); PH_EXIT_VM();
  }

  // epilogue (quadrant-ordered acc == linear mapping: qm*2*BMP*16 == mt*16)
#pragma unroll
  for (int nt = 0; nt < BNP * 2; ++nt) {
    const long col = n0 + wc * (BNP * 32) + nt * 16 + lr;
    const float bv = (MODE == 2) ? 0.f : bias[col];
#pragma unroll
    for (int mt = 0; mt < BMP * 4; ++mt) {
#pragma unroll
      for (int r = 0; r < 4; ++r) {
        const long row = m0 + wr * (BMP * 64) + mt * 16 + kg * 4 + r;
        if (MODE == 0) {
          float v = acc[mt][nt][r] + bv;
          if (col < EDIM) v *= 0.18033688011112042f;  // 0.125 * log2(e)
          ((unsigned short*)Cout)[row * QKB + col] = f2bf(v);
        } else if (MODE == 1) {
          ((float*)Cout)[row * N + col] = acc[mt][nt][r] + bv;
        } else {
          const float v = acc[mt][nt][r] + bias[row];
          ((unsigned short*)Cout)[((col >> 11) * 1024 + row) * (long)2048 +
                                  (col & 2047)] = f2bf(v);
        }
      }
    }
  }
#undef SA
#undef SB
#undef PH_ENTER
#undef PH_EXIT
#undef PH_EXIT_VM
#undef PH_EXIT_VM0
}

// ---------------------------------------------------------------------------
// Flash attention — round-10/12 configuration (verified: 89.4 µs). Unchanged.
// ---------------------------------------------------------------------------
__global__ void __launch_bounds__(512, 4) attn_fwd(const unsigned short* __restrict__ qk,
                                                   const unsigned short* __restrict__ vT,
                                                   unsigned short* __restrict__ attout) {
  const int L = blockIdx.x;
  const int bh = (L & 7) * 8 + (L >> 6);
  const int qt = (L >> 3) & 7;
  const int b = bh >> 4, h = bh & 15;
  const int q0 = qt * 256;
  const int tid = threadIdx.x, lane = tid & 63, wave = tid >> 6;  // wave 0..7
  const int lr = lane & 15, kg = lane >> 4;

  __shared__ unsigned short Ks[4][4096];   // [slot][k 64][d 64] swizzled
  __shared__ unsigned short Vs[4][4096];   // [slot][d 64][kv 64] swizzled

  const long rowbase = (long)b * SEQ;

#define ASTAGE(slot, kv0) do {                                                  \
    const int row_ = wave * 8 + (lane >> 3);                                    \
    const int col_ = ((lane & 7) ^ (lane >> 3)) << 3;                           \
    GLOAD_LDS16(qk + (rowbase + (kv0) + row_) * QKB + EDIM + h * HDIM + col_,   \
                &Ks[slot][wave * 512]);                                         \
    GLOAD_LDS16(vT + ((long)bh * HDIM + row_) * SEQ + (kv0) + col_,             \
                &Vs[slot][wave * 512]);                                         \
  } while (0)

  s16x8 qf[2][2];
#pragma unroll
  for (int qs = 0; qs < 2; ++qs) {
    const unsigned short* qp =
        qk + (rowbase + q0 + wave * 32 + qs * 16 + lr) * QKB + h * HDIM + kg * 8;
    qf[qs][0] = *(const s16x8*)qp;
    qf[qs][1] = *(const s16x8*)(qp + 32);
  }

  f32x4 l_part[2] = {{0.f, 0.f, 0.f, 0.f}, {0.f, 0.f, 0.f, 0.f}};
  f32x4 o_acc[2][4] = {};

  ASTAGE(0, 0); ASTAGE(1, 64); ASTAGE(2, 128);   // 6 loads in flight
  wait_vm<4>();                                  // tile 0 landed
  __builtin_amdgcn_s_barrier();
  __builtin_amdgcn_sched_barrier(0);

  for (int t = 0; t < 32; ++t) {
    if (t + 3 < 32) ASTAGE((t + 3) & 3, (t + 3) * 64);   // deep prefetch

    const unsigned short* Kb = Ks[t & 3];
    const unsigned short* Vb = Vs[t & 3];

    f32x4 st[2][4];
    __builtin_amdgcn_s_setprio(1);
#pragma unroll
    for (int ct = 0; ct < 4; ++ct) {
      const int rb = (ct * 16 + lr) * 128;
      const int sw = (lr & 7) << 4;
      const s16x8 k0 = *(const s16x8*)&Kb[(rb + ((kg * 16) ^ sw)) >> 1];
      const s16x8 k1 = *(const s16x8*)&Kb[(rb + ((64 + kg * 16) ^ sw)) >> 1];
#pragma unroll
      for (int qs = 0; qs < 2; ++qs) {
        f32x4 a = {};
        a = mfma_bf16(k0, qf[qs][0], a);
        a = mfma_bf16(k1, qf[qs][1], a);
        st[qs][ct] = a;
      }
    }
    __builtin_amdgcn_s_setprio(0);

    unsigned int pk[2][4][2];
#pragma unroll
    for (int qs = 0; qs < 2; ++qs) {
      f32x4 rv = {0.f, 0.f, 0.f, 0.f};
#pragma unroll
      for (int ct = 0; ct < 4; ++ct) {
        f32x4 p;
#pragma unroll
        for (int r = 0; r < 4; ++r) p[r] = fexp2(st[qs][ct][r]);
        rv += p;
        pk[qs][ct][0] = cvtpk(p[0], p[1]);
        pk[qs][ct][1] = cvtpk(p[2], p[3]);
      }
      l_part[qs] += rv;
    }

#pragma unroll
    for (int kc = 0; kc < 2; ++kc) {
      s16x8 pa[2];
#pragma unroll
      for (int qs = 0; qs < 2; ++qs) {
        u32x4 wv = {pk[qs][2 * kc][0], pk[qs][2 * kc][1],
                    pk[qs][2 * kc + 1][0], pk[qs][2 * kc + 1][1]};
        pa[qs] = __builtin_bit_cast(s16x8, wv);
      }
      __builtin_amdgcn_s_setprio(1);
#pragma unroll
      for (int dt = 0; dt < 4; ++dt) {
        const int rb = (dt * 16 + lr) * 128;
        const int c0 = (64 * kc + 8 * kg) ^ ((lr & 7) << 4);
        const s16x4 v0 = *(const s16x4*)&Vb[(rb + c0) >> 1];
        const s16x4 v1 = *(const s16x4*)&Vb[(rb + (c0 ^ 32)) >> 1];
        const s16x8 vf = __builtin_shufflevector(v0, v1, 0, 1, 2, 3, 4, 5, 6, 7);
#pragma unroll
        for (int qs = 0; qs < 2; ++qs)
          o_acc[qs][dt] = mfma_bf16(pa[qs], vf, o_acc[qs][dt]);
      }
      __builtin_amdgcn_s_setprio(0);
    }

    if (t + 1 < 32) {
      if (t + 3 < 32)      wait_vm<4>();
      else if (t + 2 < 32) wait_vm<2>();
      else                 wait_vm<0>();
      __builtin_amdgcn_s_barrier();
      __builtin_amdgcn_sched_barrier(0);
    }
  }

#pragma unroll
  for (int qs = 0; qs < 2; ++qs) {
    float rs = (l_part[qs][0] + l_part[qs][1]) + (l_part[qs][2] + l_part[qs][3]);
    rs += __shfl_xor(rs, 16, 64);
    rs += __shfl_xor(rs, 32, 64);
#pragma unroll
    for (int r = 0; r < 4; ++r) {
      const float lq = __shfl(rs, kg * 4 + r, 64);
      const float inv = 1.0f / lq;
      const long row = rowbase + q0 + wave * 32 + qs * 16 + kg * 4 + r;
#pragma unroll
      for (int dt = 0; dt < 4; ++dt)
        attout[row * EDIM + h * HDIM + dt * 16 + lr] = f2bf(o_acc[qs][dt][r] * inv);
    }
  }
#undef ASTAGE
}

extern "C" void kernel_launch(void* const* d_in, const int* in_sizes, int n_in,
                              void* d_out, int out_size, void* d_ws, size_t ws_size,
                              hipStream_t stream) {
  const float* x      = (const float*)d_in[0];
  const float* w_qkv  = (const float*)d_in[1];
  const float* b_qkv  = (const float*)d_in[2];
  const float* w_proj = (const float*)d_in[3];
  const float* b_proj = (const float*)d_in[4];

  unsigned short* xb   = (unsigned short*)d_ws;              // 8.39M elems
  unsigned short* wqb  = xb   + (size_t)MROWS * EDIM;        // 3.15M
  unsigned short* wpb  = wqb  + (size_t)NQKV * EDIM;         // 1.05M
  unsigned short* qkb  = wpb  + (size_t)EDIM * EDIM;         // 16.8M ([8192][2048])
  unsigned short* attb = qkb  + (size_t)MROWS * QKB;         // 8.39M
  unsigned short* vTb  = attb + (size_t)MROWS * EDIM;        // 8.39M ([1024][8192])

  const int sh22 = 131072;  // (2+2) x 32KB
  const int sh12 = 98304;   // (1+2) x 32KB
  const int sh21 = 98304;   // (2+1) x 32KB
  hipFuncSetAttribute((const void*)gemm8p<0, 2, 2>,
                      hipFuncAttributeMaxDynamicSharedMemorySize, sh22);
  hipFuncSetAttribute((const void*)gemm8p<2, 1, 2>,
                      hipFuncAttributeMaxDynamicSharedMemorySize, sh12);
  hipFuncSetAttribute((const void*)gemm8p<1, 2, 1>,
                      hipFuncAttributeMaxDynamicSharedMemorySize, sh21);

  cvt_all<<<12288, 256, 0, stream>>>(x, w_qkv, w_proj, xb);

  // QK projection: [8192][2048] (Q pre-scaled into log2 domain). 256 wgs.
  gemm8p<0, 2, 2><<<(MROWS / 256) * (QKB / 256), 512, sh22, stream>>>(
      xb, wqb, b_qkv, qkb, MROWS, QKB, EDIM);

  // V^T directly (swapped operands -> scattered bf16 store). 128x256 tile.
  gemm8p<2, 1, 2><<<(EDIM / 128) * (MROWS / 256), 512, sh12, stream>>>(
      wqb + (size_t)2048 * EDIM, xb, b_qkv + 2048, vTb, EDIM, MROWS, EDIM);

  attn_fwd<<<512, 512, 0, stream>>>(qkb, vTb, attb);

  // proj: 256x128 tile.
  gemm8p<1, 2, 1><<<(MROWS / 256) * (EDIM / 128), 512, sh21, stream>>>(
      attb, wpb, b_proj, d_out, MROWS, EDIM, EDIM);
}